// Round 1
// baseline (223.473 us; speedup 1.0000x reference)
//
#include <hip/hip_runtime.h>
#include <hip/hip_bf16.h>
#include <math.h>

// Problem constants
#define T_STEPS 100
#define H_DIM   50
#define Z_DIM   10
#define OUT_DIM 65   // Z + Z*(Z+1)/2 = 10 + 55

// Broadcast lane `lane`'s value of v to all lanes (returns SGPR-uniform value).
__device__ __forceinline__ float bcast(float v, int lane) {
    return __uint_as_float(__builtin_amdgcn_readlane(__float_as_uint(v), lane));
}

__global__ __launch_bounds__(256)
void gru_nat_kernel(
    const float* __restrict__ carry_init,
    const float* __restrict__ W_hr, const float* __restrict__ b_hr,
    const float* __restrict__ s_r,  const float* __restrict__ o_r,
    const float* __restrict__ W_hz, const float* __restrict__ b_hz,
    const float* __restrict__ s_z,  const float* __restrict__ o_z,
    const float* __restrict__ W_hn, const float* __restrict__ b_hn,
    const float* __restrict__ s_n,  const float* __restrict__ o_n,
    const float* __restrict__ W_dense, const float* __restrict__ b_dense,
    float* __restrict__ out)
{
    __shared__ float hs[T_STEPS][H_DIM];      // 20000 B
    __shared__ float dense[T_STEPS][OUT_DIM]; // 26000 B

    const int tid = threadIdx.x;

    // ---------------- Phase 1: recurrence (wave 0 only) ----------------
    if (tid < 64) {
        const int  j     = tid;
        const bool valid = (j < H_DIM);
        const int  jc    = valid ? j : 0;

        // Preload weight columns into registers: lane j holds column j of each W.
        float wr[H_DIM], wz[H_DIM], wn[H_DIM];
        #pragma unroll
        for (int i = 0; i < H_DIM; ++i) {
            wr[i] = W_hr[i * H_DIM + jc];
            wz[i] = W_hz[i * H_DIM + jc];
            wn[i] = W_hn[i * H_DIM + jc];
        }
        const float bhr = b_hr[jc], bhz = b_hz[jc], bhn = b_hn[jc];
        const float sr  = s_r[jc],  og_r = o_r[jc];
        const float sz  = s_z[jc],  og_z = o_z[jc];
        const float sn  = s_n[jc],  og_n = o_n[jc];

        float h = valid ? carry_init[jc] : 0.0f;
        const float invH = 1.0f / (float)H_DIM;

        #pragma unroll 1
        for (int t = 0; t < T_STEPS; ++t) {
            // Three matvecs: out_j = sum_i h_i * W[i][j] + b_j
            float ar = bhr, az = bhz, an = bhn;
            #pragma unroll
            for (int i = 0; i < H_DIM; ++i) {
                const float hi = bcast(h, i);   // v_readlane -> SGPR operand
                ar = fmaf(hi, wr[i], ar);
                az = fmaf(hi, wz[i], az);
                an = fmaf(hi, wn[i], an);
            }

            // Fused layernorm reductions: sum and sumsq for r,z,n (masked lanes >=50)
            float m_r = valid ? ar : 0.0f, q_r = valid ? ar * ar : 0.0f;
            float m_z = valid ? az : 0.0f, q_z = valid ? az * az : 0.0f;
            float m_n = valid ? an : 0.0f, q_n = valid ? an * an : 0.0f;
            #pragma unroll
            for (int s = 1; s < 64; s <<= 1) {
                m_r += __shfl_xor(m_r, s, 64);
                q_r += __shfl_xor(q_r, s, 64);
                m_z += __shfl_xor(m_z, s, 64);
                q_z += __shfl_xor(q_z, s, 64);
                m_n += __shfl_xor(m_n, s, 64);
                q_n += __shfl_xor(q_n, s, 64);
            }

            const float mu_r  = m_r * invH;
            const float var_r = fmaxf(q_r * invH - mu_r * mu_r, 0.0f);
            const float g_r   = (ar - mu_r) * rsqrtf(var_r + 1e-6f) * sr + og_r;
            const float r     = 1.0f / (1.0f + expf(-g_r));

            const float mu_z  = m_z * invH;
            const float var_z = fmaxf(q_z * invH - mu_z * mu_z, 0.0f);
            const float g_z   = (az - mu_z) * rsqrtf(var_z + 1e-6f) * sz + og_z;
            const float z     = 1.0f / (1.0f + expf(-g_z));

            const float mu_n  = m_n * invH;
            const float var_n = fmaxf(q_n * invH - mu_n * mu_n, 0.0f);
            const float g_n   = (an - mu_n) * rsqrtf(var_n + 1e-6f) * sn + og_n;
            const float n     = tanhf(r * g_n);

            h = (1.0f - z) * n + z * h;
            if (valid) hs[t][j] = h;
        }
    }
    __syncthreads();

    // ---------------- Phase 2: dense projection (all 256 threads) ----------------
    for (int idx = tid; idx < T_STEPS * OUT_DIM; idx += 256) {
        const int t = idx / OUT_DIM;
        const int o = idx - t * OUT_DIM;
        float acc = b_dense[o];
        #pragma unroll 10
        for (int i = 0; i < H_DIM; ++i)
            acc = fmaf(hs[t][i], W_dense[i * OUT_DIM + o], acc);
        dense[t][o] = acc;
    }
    __syncthreads();

    // ---------------- Phase 3: nat transform, one thread per timestep ----------------
    if (tid < T_STEPS) {
        const int t = tid;

        float mu[Z_DIM];
        #pragma unroll
        for (int i = 0; i < Z_DIM; ++i) mu[i] = dense[t][i];

        // L in packed lower-triangular form, flat index ti(i,k) = i*(i+1)/2 + k
        float L[55];
        #pragma unroll
        for (int f = 0; f < 55; ++f) L[f] = dense[t][Z_DIM + f];

        // softplus on the diagonal
        #pragma unroll
        for (int i = 0; i < Z_DIM; ++i) {
            const int  d = i * (i + 1) / 2 + i;
            const float x = L[d];
            L[d] = (x > 20.0f) ? x : log1pf(expf(x));
        }

        float* outSigma = out;           // [100][10][10]
        float* outMu    = out + 10000;   // [100][10]
        float* outJ     = out + 11000;   // [100][10][10]
        float* outHnat  = out + 21000;   // [100][10]

        // Sigma = L @ L^T (symmetric)
        #pragma unroll
        for (int a = 0; a < Z_DIM; ++a) {
            #pragma unroll
            for (int b = 0; b <= a; ++b) {
                float s = 0.0f;
                #pragma unroll
                for (int k = 0; k <= b; ++k)   // k <= min(a,b) = b
                    s = fmaf(L[a * (a + 1) / 2 + k], L[b * (b + 1) / 2 + k], s);
                outSigma[t * 100 + a * 10 + b] = s;
                outSigma[t * 100 + b * 10 + a] = s;
            }
        }

        #pragma unroll
        for (int i = 0; i < Z_DIM; ++i) outMu[t * 10 + i] = mu[i];

        // Linv via forward substitution (lower-triangular inverse)
        float Li[55];
        #pragma unroll
        for (int i = 0; i < Z_DIM; ++i) {
            const float d = 1.0f / L[i * (i + 1) / 2 + i];
            #pragma unroll
            for (int k = 0; k < i; ++k) {
                float s = 0.0f;
                #pragma unroll
                for (int m = k; m < i; ++m)
                    s = fmaf(L[i * (i + 1) / 2 + m], Li[m * (m + 1) / 2 + k], s);
                Li[i * (i + 1) / 2 + k] = -s * d;
            }
            Li[i * (i + 1) / 2 + i] = d;
        }

        // J = Linv^T @ Linv (symmetric), h_nat = J @ mu
        float hn[Z_DIM];
        #pragma unroll
        for (int a = 0; a < Z_DIM; ++a) hn[a] = 0.0f;

        #pragma unroll
        for (int a = 0; a < Z_DIM; ++a) {
            #pragma unroll
            for (int b = 0; b <= a; ++b) {
                float s = 0.0f;
                #pragma unroll
                for (int m = a; m < Z_DIM; ++m)   // m >= max(a,b) = a
                    s = fmaf(Li[m * (m + 1) / 2 + a], Li[m * (m + 1) / 2 + b], s);
                outJ[t * 100 + a * 10 + b] = s;
                outJ[t * 100 + b * 10 + a] = s;
                hn[a] = fmaf(s, mu[b], hn[a]);
                if (b < a) hn[b] = fmaf(s, mu[a], hn[b]);
            }
        }
        #pragma unroll
        for (int a = 0; a < Z_DIM; ++a) outHnat[t * 10 + a] = hn[a];
    }
}

extern "C" void kernel_launch(void* const* d_in, const int* in_sizes, int n_in,
                              void* d_out, int out_size, void* d_ws, size_t ws_size,
                              hipStream_t stream) {
    const float* p[15];
    for (int i = 0; i < 15; ++i) p[i] = (const float*)d_in[i];
    gru_nat_kernel<<<dim3(1), dim3(256), 0, stream>>>(
        p[0],            // carry_init
        p[1], p[2], p[3], p[4],     // W_hr, b_hr, s_r, o_r
        p[5], p[6], p[7], p[8],     // W_hz, b_hz, s_z, o_z
        p[9], p[10], p[11], p[12],  // W_hn, b_hn, s_n, o_n
        p[13], p[14],               // W_dense, b_dense
        (float*)d_out);
}

// Round 2
// 168.762 us; speedup vs baseline: 1.3242x; 1.3242x over previous
//
#include <hip/hip_runtime.h>
#include <hip/hip_bf16.h>
#include <math.h>

// Problem constants
#define T_STEPS 100
#define H_DIM   50
#define Z_DIM   10
#define OUT_DIM 65   // Z + Z*(Z+1)/2 = 10 + 55

typedef float v2f __attribute__((ext_vector_type(2)));

// Broadcast lane `lane`'s value of v to all lanes (v_readlane -> SGPR).
__device__ __forceinline__ float bcast_lane(float v, int lane) {
    return __uint_as_float(__builtin_amdgcn_readlane(__float_as_uint(v), lane));
}

// DPP cross-lane fetch (VALU speed). bound_ctrl=1 -> OOB reads 0.
template<int CTRL>
__device__ __forceinline__ float dpp_mov(float x) {
    return __uint_as_float((unsigned)__builtin_amdgcn_update_dpp(
        0, (int)__float_as_uint(x), CTRL, 0xF, 0xF, true));
}

#define DPP_QUAD_XOR1 0xB1   // quad_perm(1,0,3,2)
#define DPP_QUAD_XOR2 0x4E   // quad_perm(2,3,0,1)
#define DPP_HALF_MIRR 0x141  // row_half_mirror (xor-4 once quads uniform)
#define DPP_ROW_MIRR  0x140  // row_mirror (xor-8 once 8-groups uniform)

// ds_swizzle xor-16 within 32-lane halves: offset = (16<<10) | 0x1F
__device__ __forceinline__ float swz_xor16(float x) {
    return __uint_as_float((unsigned)__builtin_amdgcn_ds_swizzle(
        (int)__float_as_uint(x), 0x401F));
}

__device__ __forceinline__ float fast_rcp(float x) { return __builtin_amdgcn_rcpf(x); }
__device__ __forceinline__ float fast_rsq(float x) { return __builtin_amdgcn_rsqf(x); }
__device__ __forceinline__ float fast_sigmoid(float x) {
    return fast_rcp(1.0f + __expf(-x));
}
__device__ __forceinline__ float fast_tanh(float y) {
    // tanh(y) = 1 - 2/(exp(2y)+1); exp overflow -> inf -> rcp -> 0 -> 1. Underflow -> -1.
    return 1.0f - 2.0f * fast_rcp(__expf(2.0f * y) + 1.0f);
}

__global__ __launch_bounds__(256, 1)
void gru_nat_kernel(
    const float* __restrict__ carry_init,
    const float* __restrict__ W_hr, const float* __restrict__ b_hr,
    const float* __restrict__ s_r,  const float* __restrict__ o_r,
    const float* __restrict__ W_hz, const float* __restrict__ b_hz,
    const float* __restrict__ s_z,  const float* __restrict__ o_z,
    const float* __restrict__ W_hn, const float* __restrict__ b_hn,
    const float* __restrict__ s_n,  const float* __restrict__ o_n,
    const float* __restrict__ W_dense, const float* __restrict__ b_dense,
    float* __restrict__ out)
{
    __shared__ float hs[T_STEPS][H_DIM];      // 20000 B
    __shared__ float dense[T_STEPS][OUT_DIM]; // 26000 B

    const int tid = threadIdx.x;

    // ---------------- Phase 1: recurrence (wave 0 only) ----------------
    if (tid < 64) {
        const int  j     = tid;
        const bool valid = (j < H_DIM);
        const int  jc    = valid ? j : 0;

        // Lane j holds column j of each W, in registers.
        // r/z columns packed as float2 -> v_pk_fma_f32 in the matvec.
        v2f   wrz[H_DIM];
        float wn [H_DIM];
        #pragma unroll
        for (int i = 0; i < H_DIM; ++i) {
            wrz[i] = (v2f){ W_hr[i * H_DIM + jc], W_hz[i * H_DIM + jc] };
            wn [i] = W_hn[i * H_DIM + jc];
        }
        const float bhr = b_hr[jc], bhz = b_hz[jc], bhn = b_hn[jc];
        const float sr  = s_r[jc],  og_r = o_r[jc];
        const float sz  = s_z[jc],  og_z = o_z[jc];
        const float sn  = s_n[jc],  og_n = o_n[jc];

        float h = valid ? carry_init[jc] : 0.0f;
        const float invH = 1.0f / (float)H_DIM;

        #pragma unroll 1
        for (int t = 0; t < T_STEPS; ++t) {
            // ---- three matvecs: a_j = sum_i h_i * W[i][j] + b_j ----
            v2f   arz = (v2f){ bhr, bhz };
            float an  = bhn;
            #pragma unroll
            for (int i = 0; i < H_DIM; ++i) {
                const float hi = bcast_lane(h, i);   // SGPR broadcast
                const v2f   hv = (v2f){ hi, hi };
                arz = __builtin_elementwise_fma(hv, wrz[i], arz);
                an  = fmaf(hi, wn[i], an);
            }
            const float ar = arz.x, az = arz.y;

            // ---- fused layernorm reductions: sum & sumsq for r,z,n ----
            float m_r = valid ? ar : 0.0f, q_r = valid ? ar * ar : 0.0f;
            float m_z = valid ? az : 0.0f, q_z = valid ? az * az : 0.0f;
            float m_n = valid ? an : 0.0f, q_n = valid ? an * an : 0.0f;

            #define RED_STAGE_DPP(CTRL)                         \
                m_r += dpp_mov<CTRL>(m_r); q_r += dpp_mov<CTRL>(q_r); \
                m_z += dpp_mov<CTRL>(m_z); q_z += dpp_mov<CTRL>(q_z); \
                m_n += dpp_mov<CTRL>(m_n); q_n += dpp_mov<CTRL>(q_n);

            RED_STAGE_DPP(DPP_QUAD_XOR1)   // xor 1
            RED_STAGE_DPP(DPP_QUAD_XOR2)   // xor 2
            RED_STAGE_DPP(DPP_HALF_MIRR)   // xor 4 (quads uniform)
            RED_STAGE_DPP(DPP_ROW_MIRR)    // xor 8 (8-groups uniform)
            #undef RED_STAGE_DPP

            // xor 16 within each 32-lane half (LDS swizzle pipe)
            m_r += swz_xor16(m_r); q_r += swz_xor16(q_r);
            m_z += swz_xor16(m_z); q_z += swz_xor16(q_z);
            m_n += swz_xor16(m_n); q_n += swz_xor16(q_n);

            // xor 32 across halves (ds_bpermute)
            m_r += __shfl_xor(m_r, 32, 64); q_r += __shfl_xor(q_r, 32, 64);
            m_z += __shfl_xor(m_z, 32, 64); q_z += __shfl_xor(q_z, 32, 64);
            m_n += __shfl_xor(m_n, 32, 64); q_n += __shfl_xor(q_n, 32, 64);

            // ---- layernorm + activations ----
            const float mu_r  = m_r * invH;
            const float var_r = fmaxf(q_r * invH - mu_r * mu_r, 0.0f);
            const float g_r   = (ar - mu_r) * fast_rsq(var_r + 1e-6f) * sr + og_r;
            const float r     = fast_sigmoid(g_r);

            const float mu_z  = m_z * invH;
            const float var_z = fmaxf(q_z * invH - mu_z * mu_z, 0.0f);
            const float g_z   = (az - mu_z) * fast_rsq(var_z + 1e-6f) * sz + og_z;
            const float z     = fast_sigmoid(g_z);

            const float mu_n  = m_n * invH;
            const float var_n = fmaxf(q_n * invH - mu_n * mu_n, 0.0f);
            const float g_n   = (an - mu_n) * fast_rsq(var_n + 1e-6f) * sn + og_n;
            const float n     = fast_tanh(r * g_n);

            h = n + z * (h - n);   // (1-z)*n + z*h
            if (valid) hs[t][j] = h;
        }
    }
    __syncthreads();

    // ---------------- Phase 2: dense projection (all 256 threads) ----------------
    for (int idx = tid; idx < T_STEPS * OUT_DIM; idx += 256) {
        const int t = idx / OUT_DIM;
        const int o = idx - t * OUT_DIM;
        float acc = b_dense[o];
        #pragma unroll 10
        for (int i = 0; i < H_DIM; ++i)
            acc = fmaf(hs[t][i], W_dense[i * OUT_DIM + o], acc);
        dense[t][o] = acc;
    }
    __syncthreads();

    // ---------------- Phase 3: nat transform, one thread per timestep ----------------
    if (tid < T_STEPS) {
        const int t = tid;

        float mu[Z_DIM];
        #pragma unroll
        for (int i = 0; i < Z_DIM; ++i) mu[i] = dense[t][i];

        // L packed lower-triangular, flat index i*(i+1)/2 + k
        float L[55];
        #pragma unroll
        for (int f = 0; f < 55; ++f) L[f] = dense[t][Z_DIM + f];

        // softplus on the diagonal (log1p kept for tiny-x safety)
        #pragma unroll
        for (int i = 0; i < Z_DIM; ++i) {
            const int  d = i * (i + 1) / 2 + i;
            const float x = L[d];
            L[d] = (x > 20.0f) ? x : log1pf(__expf(x));
        }

        float* outSigma = out;           // [100][10][10]
        float* outMu    = out + 10000;   // [100][10]
        float* outJ     = out + 11000;   // [100][10][10]
        float* outHnat  = out + 21000;   // [100][10]

        // Sigma = L @ L^T (symmetric)
        #pragma unroll
        for (int a = 0; a < Z_DIM; ++a) {
            #pragma unroll
            for (int b = 0; b <= a; ++b) {
                float s = 0.0f;
                #pragma unroll
                for (int k = 0; k <= b; ++k)
                    s = fmaf(L[a * (a + 1) / 2 + k], L[b * (b + 1) / 2 + k], s);
                outSigma[t * 100 + a * 10 + b] = s;
                outSigma[t * 100 + b * 10 + a] = s;
            }
        }

        #pragma unroll
        for (int i = 0; i < Z_DIM; ++i) outMu[t * 10 + i] = mu[i];

        // Linv via forward substitution
        float Li[55];
        #pragma unroll
        for (int i = 0; i < Z_DIM; ++i) {
            const float d = 1.0f / L[i * (i + 1) / 2 + i];
            #pragma unroll
            for (int k = 0; k < i; ++k) {
                float s = 0.0f;
                #pragma unroll
                for (int m = k; m < i; ++m)
                    s = fmaf(L[i * (i + 1) / 2 + m], Li[m * (m + 1) / 2 + k], s);
                Li[i * (i + 1) / 2 + k] = -s * d;
            }
            Li[i * (i + 1) / 2 + i] = d;
        }

        // J = Linv^T @ Linv (symmetric), h_nat = J @ mu
        float hn[Z_DIM];
        #pragma unroll
        for (int a = 0; a < Z_DIM; ++a) hn[a] = 0.0f;

        #pragma unroll
        for (int a = 0; a < Z_DIM; ++a) {
            #pragma unroll
            for (int b = 0; b <= a; ++b) {
                float s = 0.0f;
                #pragma unroll
                for (int m = a; m < Z_DIM; ++m)
                    s = fmaf(Li[m * (m + 1) / 2 + a], Li[m * (m + 1) / 2 + b], s);
                outJ[t * 100 + a * 10 + b] = s;
                outJ[t * 100 + b * 10 + a] = s;
                hn[a] = fmaf(s, mu[b], hn[a]);
                if (b < a) hn[b] = fmaf(s, mu[a], hn[b]);
            }
        }
        #pragma unroll
        for (int a = 0; a < Z_DIM; ++a) outHnat[t * 10 + a] = hn[a];
    }
}

extern "C" void kernel_launch(void* const* d_in, const int* in_sizes, int n_in,
                              void* d_out, int out_size, void* d_ws, size_t ws_size,
                              hipStream_t stream) {
    const float* p[15];
    for (int i = 0; i < 15; ++i) p[i] = (const float*)d_in[i];
    gru_nat_kernel<<<dim3(1), dim3(256), 0, stream>>>(
        p[0],
        p[1], p[2], p[3], p[4],
        p[5], p[6], p[7], p[8],
        p[9], p[10], p[11], p[12],
        p[13], p[14],
        (float*)d_out);
}

// Round 3
// 146.140 us; speedup vs baseline: 1.5292x; 1.1548x over previous
//
#include <hip/hip_runtime.h>
#include <hip/hip_bf16.h>
#include <math.h>

// Problem constants
#define T_STEPS 100
#define H_DIM   50
#define Z_DIM   10
#define OUT_DIM 65   // Z + Z*(Z+1)/2 = 10 + 55

// Broadcast lane `lane`'s value of v to all lanes (v_readlane -> SGPR).
__device__ __forceinline__ float bcast_lane(float v, int lane) {
    return __uint_as_float(__builtin_amdgcn_readlane(__float_as_uint(v), lane));
}

// DPP cross-lane fetch (VALU speed). bound_ctrl=1 -> invalid source reads 0.
template<int CTRL>
__device__ __forceinline__ float dpp_mov(float x) {
    return __uint_as_float((unsigned)__builtin_amdgcn_update_dpp(
        0, (int)__float_as_uint(x), CTRL, 0xF, 0xF, true));
}

#define DPP_SHR1    0x111
#define DPP_SHR2    0x112
#define DPP_SHR4    0x114
#define DPP_SHR8    0x118
#define DPP_BCAST15 0x142
#define DPP_BCAST31 0x143

// Full-wave sum of two quantities, interleaved for ILP. Pure VALU (DPP),
// no LDS. Result: total broadcast to all lanes via readlane 63.
__device__ __forceinline__ void wave_sum2(float& a, float& b) {
    a += dpp_mov<DPP_SHR1>(a);    b += dpp_mov<DPP_SHR1>(b);
    a += dpp_mov<DPP_SHR2>(a);    b += dpp_mov<DPP_SHR2>(b);
    a += dpp_mov<DPP_SHR4>(a);    b += dpp_mov<DPP_SHR4>(b);
    a += dpp_mov<DPP_SHR8>(a);    b += dpp_mov<DPP_SHR8>(b);
    a += dpp_mov<DPP_BCAST15>(a); b += dpp_mov<DPP_BCAST15>(b);
    a += dpp_mov<DPP_BCAST31>(a); b += dpp_mov<DPP_BCAST31>(b);
    a = bcast_lane(a, 63);
    b = bcast_lane(b, 63);
}

__device__ __forceinline__ float fast_rcp(float x) { return __builtin_amdgcn_rcpf(x); }
__device__ __forceinline__ float fast_rsq(float x) { return __builtin_amdgcn_rsqf(x); }
__device__ __forceinline__ float fast_sigmoid(float x) {
    return fast_rcp(1.0f + __expf(-x));
}
__device__ __forceinline__ float fast_tanh(float y) {
    // tanh(y) = 1 - 2/(exp(2y)+1); overflow-safe at both ends.
    return 1.0f - 2.0f * fast_rcp(__expf(2.0f * y) + 1.0f);
}

__global__ __launch_bounds__(256, 1)
void gru_nat_kernel(
    const float* __restrict__ carry_init,
    const float* __restrict__ W_hr, const float* __restrict__ b_hr,
    const float* __restrict__ s_r,  const float* __restrict__ o_r,
    const float* __restrict__ W_hz, const float* __restrict__ b_hz,
    const float* __restrict__ s_z,  const float* __restrict__ o_z,
    const float* __restrict__ W_hn, const float* __restrict__ b_hn,
    const float* __restrict__ s_n,  const float* __restrict__ o_n,
    const float* __restrict__ W_dense, const float* __restrict__ b_dense,
    float* __restrict__ out)
{
    __shared__ float hs[T_STEPS][H_DIM];       // 20000 B
    __shared__ float dense[T_STEPS][OUT_DIM];  // 26000 B
    __shared__ float share[2][3][64];          // 1536 B (double-buffered r/z/gn)

    const int tid  = threadIdx.x;
    const int wave = tid >> 6;
    const int lane = tid & 63;

    // ---------------- Phase 1: recurrence, one gate per wave ----------------
    if (wave < 3) {
        const bool valid = (lane < H_DIM);
        const int  jc    = valid ? lane : 0;

        const float* __restrict__ Wg = (wave == 0) ? W_hr : (wave == 1) ? W_hz : W_hn;
        const float* __restrict__ bg = (wave == 0) ? b_hr : (wave == 1) ? b_hz : b_hn;
        const float* __restrict__ sg = (wave == 0) ? s_r  : (wave == 1) ? s_z  : s_n;
        const float* __restrict__ og = (wave == 0) ? o_r  : (wave == 1) ? o_z  : o_n;

        // Lane j holds column j of this gate's W: only 50 floats/lane -> no spill.
        float w[H_DIM];
        #pragma unroll
        for (int i = 0; i < H_DIM; ++i) w[i] = Wg[i * H_DIM + jc];
        const float bj = bg[jc], sj = sg[jc], oj = og[jc];

        float h = valid ? carry_init[jc] : 0.0f;
        const float invH = 1.0f / (float)H_DIM;

        #pragma unroll 1
        for (int t = 0; t < T_STEPS; ++t) {
            // matvec: a_j = b_j + sum_i h_i * W[i][j]; 4 accumulators break the chain
            float a0 = bj, a1 = 0.0f, a2 = 0.0f, a3 = 0.0f;
            #pragma unroll
            for (int i = 0; i < 48; i += 4) {
                a0 = fmaf(bcast_lane(h, i + 0), w[i + 0], a0);
                a1 = fmaf(bcast_lane(h, i + 1), w[i + 1], a1);
                a2 = fmaf(bcast_lane(h, i + 2), w[i + 2], a2);
                a3 = fmaf(bcast_lane(h, i + 3), w[i + 3], a3);
            }
            a0 = fmaf(bcast_lane(h, 48), w[48], a0);
            a1 = fmaf(bcast_lane(h, 49), w[49], a1);
            const float a = (a0 + a2) + (a1 + a3);

            // layernorm stats (masked lanes contribute 0), pure-DPP reduction
            float m = valid ? a     : 0.0f;
            float q = valid ? a * a : 0.0f;
            wave_sum2(m, q);

            const float mu   = m * invH;
            const float var  = fmaxf(q * invH - mu * mu, 0.0f);
            const float gval = (a - mu) * fast_rsq(var + 1e-6f) * sj + oj;

            // waves 0/1 share sigmoid(g); wave 2 shares raw g (n pre-activation)
            const float sv = (wave == 2) ? gval : fast_sigmoid(gval);
            share[t & 1][wave][lane] = sv;
            __syncthreads();

            const float r  = share[t & 1][0][lane];
            const float z  = share[t & 1][1][lane];
            const float gn = share[t & 1][2][lane];
            const float n  = fast_tanh(r * gn);
            h = n + z * (h - n);                 // (1-z)*n + z*h
            if (wave == 0 && valid) hs[t][lane] = h;
        }
    } else {
        // wave 3: match the barrier count
        #pragma unroll 1
        for (int t = 0; t < T_STEPS; ++t) __syncthreads();
    }
    __syncthreads();

    // ---------------- Phase 2: dense projection (all 256 threads) ----------------
    for (int idx = tid; idx < T_STEPS * OUT_DIM; idx += 256) {
        const int t = idx / OUT_DIM;
        const int o = idx - t * OUT_DIM;
        float acc = b_dense[o];
        #pragma unroll 10
        for (int i = 0; i < H_DIM; ++i)
            acc = fmaf(hs[t][i], W_dense[i * OUT_DIM + o], acc);
        dense[t][o] = acc;
    }
    __syncthreads();

    // ---------------- Phase 3: nat transform, one thread per timestep ----------------
    if (tid < T_STEPS) {
        const int t = tid;

        float mu[Z_DIM];
        #pragma unroll
        for (int i = 0; i < Z_DIM; ++i) mu[i] = dense[t][i];

        // L packed lower-triangular, flat index tri(i)+k, tri(i)=i*(i+1)/2
        float L[55];
        #pragma unroll
        for (int f = 0; f < 55; ++f) L[f] = dense[t][Z_DIM + f];

        // softplus on the diagonal
        #pragma unroll
        for (int i = 0; i < Z_DIM; ++i) {
            const int   d = i * (i + 1) / 2 + i;
            const float x = L[d];
            L[d] = (x > 20.0f) ? x : log1pf(__expf(x));
        }

        float* outSigma = out;           // [100][10][10]
        float* outMu    = out + 10000;   // [100][10]
        float* outJ     = out + 11000;   // [100][10][10]
        float* outHnat  = out + 21000;   // [100][10]

        // Sigma = L @ L^T (symmetric) — uses L only, before in-place inversion
        #pragma unroll
        for (int a = 0; a < Z_DIM; ++a) {
            #pragma unroll
            for (int b = 0; b <= a; ++b) {
                float s = 0.0f;
                #pragma unroll
                for (int k = 0; k <= b; ++k)
                    s = fmaf(L[a * (a + 1) / 2 + k], L[b * (b + 1) / 2 + k], s);
                outSigma[t * 100 + a * 10 + b] = s;
                outSigma[t * 100 + b * 10 + a] = s;
            }
        }

        #pragma unroll
        for (int i = 0; i < Z_DIM; ++i) outMu[t * 10 + i] = mu[i];

        // In-place lower-triangular inversion (row i overwritten after use):
        // rows m < i already hold Linv; row i of L is consumed via tmp.
        #pragma unroll
        for (int i = 0; i < Z_DIM; ++i) {
            const float d = 1.0f / L[i * (i + 1) / 2 + i];
            float tmp[Z_DIM];
            #pragma unroll
            for (int k = 0; k < Z_DIM - 1; ++k) tmp[k] = 0.0f;
            #pragma unroll
            for (int k = 0; k < i; ++k) {
                float s = 0.0f;
                #pragma unroll
                for (int m = k; m < i; ++m)
                    s = fmaf(L[i * (i + 1) / 2 + m], L[m * (m + 1) / 2 + k], s);
                tmp[k] = -s * d;
            }
            #pragma unroll
            for (int k = 0; k < i; ++k) L[i * (i + 1) / 2 + k] = tmp[k];
            L[i * (i + 1) / 2 + i] = d;
        }
        // L now holds Linv

        // J = Linv^T @ Linv (symmetric), h_nat = J @ mu
        float hn[Z_DIM];
        #pragma unroll
        for (int a = 0; a < Z_DIM; ++a) hn[a] = 0.0f;

        #pragma unroll
        for (int a = 0; a < Z_DIM; ++a) {
            #pragma unroll
            for (int b = 0; b <= a; ++b) {
                float s = 0.0f;
                #pragma unroll
                for (int m = a; m < Z_DIM; ++m)
                    s = fmaf(L[m * (m + 1) / 2 + a], L[m * (m + 1) / 2 + b], s);
                outJ[t * 100 + a * 10 + b] = s;
                outJ[t * 100 + b * 10 + a] = s;
                hn[a] = fmaf(s, mu[b], hn[a]);
                if (b < a) hn[b] = fmaf(s, mu[a], hn[b]);
            }
        }
        #pragma unroll
        for (int a = 0; a < Z_DIM; ++a) outHnat[t * 10 + a] = hn[a];
    }
}

extern "C" void kernel_launch(void* const* d_in, const int* in_sizes, int n_in,
                              void* d_out, int out_size, void* d_ws, size_t ws_size,
                              hipStream_t stream) {
    const float* p[15];
    for (int i = 0; i < 15; ++i) p[i] = (const float*)d_in[i];
    gru_nat_kernel<<<dim3(1), dim3(256), 0, stream>>>(
        p[0],
        p[1], p[2], p[3], p[4],
        p[5], p[6], p[7], p[8],
        p[9], p[10], p[11], p[12],
        p[13], p[14],
        (float*)d_out);
}